// Round 11
// baseline (912.191 us; speedup 1.0000x reference)
//
#include <hip/hip_runtime.h>

// Problem constants
static constexpr int P = 16384;           // 128*128 plane

// Workspace layout (float offsets). Total ~43.5 MB.
static constexpr int OFF_H1   = 0;         // 24 planes (post-relu act layer1)
static constexpr int OFF_H2   = 24 * P;    // 24
static constexpr int OFF_H3   = 48 * P;    // 24
static constexpr int OFF_H4   = 72 * P;    // 24
static constexpr int OFF_OUT5 = 96 * P;    // 12 (kappa,v1,v2,f,u_rk[8])
static constexpr int OFF_GA   = 108 * P;   // backward ping; ALSO holds bcot table (consumed by dz3 before dz2 overwrites)
static constexpr int OFF_GB   = 372 * P;   // backward pong; also 18-ch input stage
static constexpr int OFF_DXY  = 636 * P;   // 22 planes: per cot [dx, dy] interleaved
static constexpr int OFF_W    = 658 * P;   // packed weights

// packed weight sub-offsets (relative to OFF_W), layout [tap][cin][cout]
static constexpr int PW1 = 0;        // 25*18*24 = 10800
static constexpr int PW2 = 10800;    // 25*24*24 = 14400
static constexpr int PW3 = 25200;
static constexpr int PW4 = 39600;
static constexpr int PW5 = 54000;    // 25*24*12 = 7200
static constexpr int PB4 = 61200;    // transposed+flipped for backward
static constexpr int PB3 = 75600;
static constexpr int PB2 = 90000;
static constexpr int PB1 = 104400;   // 25*24*2 = 1200

// ---------------------------------------------------------------------------
// Repack weights + build the conv5^T one-hot/all-ones cotangent table.
// ---------------------------------------------------------------------------
__global__ void pack_weights(const float* __restrict__ W1, const float* __restrict__ W2,
                             const float* __restrict__ W3, const float* __restrict__ W4,
                             const float* __restrict__ W5, float* __restrict__ wp,
                             float* __restrict__ tbl) {
    int i = blockIdx.x * 256 + threadIdx.x;
    if (i < 10800) {                       // W1p [25][18][24]
        int co = i % 24, ci = (i / 24) % 18, t = i / 432;
        wp[PW1 + i] = W1[(co * 18 + ci) * 25 + t];
    }
    if (i < 14400) {                       // W2p/W3p/W4p + B4/B3/B2
        int co = i % 24, ci = (i / 24) % 24, t = i / 576;
        wp[PW2 + i] = W2[(co * 24 + ci) * 25 + t];
        wp[PW3 + i] = W3[(co * 24 + ci) * 25 + t];
        wp[PW4 + i] = W4[(co * 24 + ci) * 25 + t];
        int cin = i % 24, cout = (i / 24) % 24, tb = i / 576;
        wp[PB4 + i] = W4[(cout * 24 + cin) * 25 + (24 - tb)];
        wp[PB3 + i] = W3[(cout * 24 + cin) * 25 + (24 - tb)];
        wp[PB2 + i] = W2[(cout * 24 + cin) * 25 + (24 - tb)];
    }
    if (i < 7200) {                        // W5p [25][24][12]
        int co = i % 12, ci = (i / 12) % 24, t = i / 288;
        wp[PW5 + i] = W5[(co * 24 + ci) * 25 + t];
    }
    if (i < 1200) {                        // B1 [25][24][2] (only input ch 0,1 needed)
        int ci = i % 2, co = (i / 2) % 24, t = i / 48;
        wp[PB1 + i] = W1[(co * 18 + ci) * 25 + (24 - t)];
    }
    if (i < 6600) {                        // bcot table [11][24][5][5]
        int cx = i % 5, cy = (i / 5) % 5, ci = (i / 25) % 24, cot = i / 600;
        int oc = (cot < 3) ? cot : cot + 1;
        int a0 = (cy <= 2) ? 0 : cy - 2, a1 = (cy >= 2) ? 4 : cy + 2;
        int b0 = (cx <= 2) ? 0 : cx - 2, b1 = (cx >= 2) ? 4 : cx + 2;
        const float* __restrict__ w = W5 + (oc * 24 + ci) * 25;
        float s = 0.f;
        for (int a = a0; a <= a1; ++a)
            for (int b = b0; b <= b1; ++b) s += w[a * 5 + b];
        tbl[i] = s;
    }
}

// Stage x,y,u as a contiguous 18-plane tensor
__global__ void stage_input(const float* __restrict__ x, const float* __restrict__ y,
                            const float* __restrict__ u, float* __restrict__ in18) {
    int i = blockIdx.x * 256 + threadIdx.x;   // 18*P threads
    int pl = i / P, p = i - pl * P;
    float v = (pl == 0) ? x[p] : (pl == 1) ? y[p] : u[(pl - 2) * P + p];
    in18[i] = v;
}

// ---------------------------------------------------------------------------
// Generic 5x5 SAME conv over 128x128 planes.
//  - Geometry = round-6/10 Pareto point (256 thr, 16x16 tile, CHUNK=12).
//  - r10 post-mortem: removing staging VALU made backward SLOWER at lower
//    VALUBusy => stall-bound on the serial stage->barrier->compute chain,
//    not issue-bound. r11: T14 async-STAGE split — issue chunk k+1's global
//    loads into REGISTERS before chunk k's FMA phase (load latency hides
//    under ~7200 cyc of FMAs), then regs->LDS after the barrier. LDS stays
//    single-buffered; dbuf is through VGPRs (+24 regs, capped by
//    __launch_bounds__(.,6) => no spill).
//  - staging slots precomputed once (r10); goff clamped so loads are always
//    in-bounds, validity applied by cndmask at write time.
//  - halo LDS stride SW=24 -> 2-way bank aliasing on FMA reads (free).
//  - weights packed [tap][cin][cout]; inner co loop reads contiguous
//    block-uniform addresses -> s_load, SGPR operand in v_fmac.
//  - BATCH: blockIdx.z folds (cotangent, channel-split).
//  - MASK: multiply output by (mask_plane > 0) -> relu backward.
//  - TBL: stage (h4>0 ? border-class table : 0) (bcot_init folded into dz3;
//    'inbase' is h4, unbatched). Table gather stays at write time (L1-hot).
// ---------------------------------------------------------------------------
template <int NTY, int TW, int SW, int CIN, int CHUNK, int COUT_TOT, int COB,
          bool RELU, bool MASK, bool BATCH, bool TBL>
__global__ __launch_bounds__(NTY * TW, 6) void conv5x5(
    const float* __restrict__ inbase, const float* __restrict__ wp,
    const float* __restrict__ bias, const float* __restrict__ maskbase,
    const float* __restrict__ tbl, float* __restrict__ outbase) {
    constexpr int NSPL = COUT_TOT / COB;
    constexpr int TR = NTY;                // tile rows
    constexpr int HR = TR + 4;             // halo rows
    constexpr int HC = TW + 4;             // halo cols (logical)
    constexpr int NT = NTY * TW;           // threads
    constexpr int HTOT = HR * HC;          // halo elements per channel
    constexpr int NSLOT = (HTOT + NT - 1) / NT;
    constexpr int NCHUNK = CIN / CHUNK;
    static_assert(CIN % CHUNK == 0, "CHUNK must divide CIN");
    const int z = blockIdx.z;
    const int half = z % NSPL;
    const int cot = z / NSPL;
    const float* in = inbase + ((BATCH && !TBL) ? cot * CIN * P : 0);
    float* out = outbase + (BATCH ? cot * COUT_TOT * P : 0);
    const int cobase = half * COB;

    __shared__ float smem[CHUNK][HR][SW];
    const int tid = threadIdx.x;
    const int bx = blockIdx.x, by = blockIdx.y;
    const int ty = tid / TW, tx = tid % TW;

    // ---- precompute staging slots (once per kernel) ----
    bool s_store[NSLOT];     // element index in range
    bool s_valid[NSLOT];     // global coords in range (else zero-fill)
    int  s_goff[NSLOT];      // gy*128+gx, clamped to 0 when invalid
    int  s_lds[NSLOT];       // r*SW+c (float index)
    int  s_tcls[NSLOT];      // TBL: cy*5+cx
#pragma unroll
    for (int s = 0; s < NSLOT; ++s) {
        int i = tid + s * NT;
        int r = i / HC, c = i % HC;
        int gy = by * TR + r - 2, gx = bx * TW + c - 2;
        s_store[s] = (i < HTOT);
        s_valid[s] = (i < HTOT) && ((unsigned)gy < 128u) && ((unsigned)gx < 128u);
        s_goff[s]  = s_valid[s] ? (gy * 128 + gx) : 0;
        s_lds[s]   = r * SW + c;
        if (TBL) {
            int cy = (gy < 2) ? gy : (gy > 125) ? gy - 123 : 2;
            int cx = (gx < 2) ? gx : (gx > 125) ? gx - 123 : 2;
            s_tcls[s] = cy * 5 + cx;
        }
    }

    float rv[NSLOT][CHUNK];              // in-flight staged values

    // issue the global loads for chunk starting at c0 (always in-bounds)
    auto load_chunk = [&](int c0) {
#pragma unroll
        for (int s = 0; s < NSLOT; ++s) {
            const float* gb = in + c0 * P + s_goff[s];
#pragma unroll
            for (int ci = 0; ci < CHUNK; ++ci) rv[s][ci] = gb[ci * P];
        }
    };
    // regs -> LDS (validity select; TBL gather here, table is L1-hot)
    auto write_chunk = [&](int c0) {
#pragma unroll
        for (int s = 0; s < NSLOT; ++s) {
            if (s_store[s]) {
                float* lb = &smem[0][0][0] + s_lds[s];
#pragma unroll
                for (int ci = 0; ci < CHUNK; ++ci) {
                    float v = 0.f;
                    if (s_valid[s]) {
                        if (TBL) {
                            if (rv[s][ci] > 0.f)
                                v = tbl[(cot * CIN + c0 + ci) * 25 + s_tcls[s]];
                        } else {
                            v = rv[s][ci];
                        }
                    }
                    lb[ci * HR * SW] = v;
                }
            }
        }
    };

    float acc[COB];
#pragma unroll
    for (int co = 0; co < COB; ++co) acc[co] = bias ? bias[cobase + co] : 0.f;

    // prologue: stage chunk 0 (latency exposed once)
    load_chunk(0);
    write_chunk(0);
    __syncthreads();

#pragma unroll
    for (int k = 0; k < NCHUNK; ++k) {
        const int c0 = k * CHUNK;
        if (k + 1 < NCHUNK) load_chunk(c0 + CHUNK);   // issue early: hides under FMAs

        for (int a = 0; a < 5; ++a) {
            for (int b = 0; b < 5; ++b) {
                const float* __restrict__ wrow =
                    wp + ((a * 5 + b) * CIN + c0) * COUT_TOT + cobase;
                for (int ci = 0; ci < CHUNK; ++ci) {
                    float v = smem[ci][ty + a][tx + b];
#pragma unroll
                    for (int co = 0; co < COB; ++co)
                        acc[co] = fmaf(v, wrow[ci * COUT_TOT + co], acc[co]);
                }
            }
        }

        if (k + 1 < NCHUNK) {
            __syncthreads();                 // everyone done reading chunk k
            write_chunk(c0 + CHUNK);         // write-late: loads have landed
            __syncthreads();                 // writes visible
        }
    }

    const int gy = by * TR + ty, gx = bx * TW + tx, gp = gy * 128 + gx;
#pragma unroll
    for (int co = 0; co < COB; ++co) {
        float v = acc[co];
        if (RELU) v = v > 0.f ? v : 0.f;
        if (MASK) v = (maskbase[(cobase + co) * P + gp] > 0.f) ? v : 0.f;
        out[(cobase + co) * P + gp] = v;
    }
}

// ---------------------------------------------------------------------------
// Finalize: pde[q] = (kappa_x+v1)*u_rk_x[q] + (kappa_y+v2)*u_rk_y[q] + f
// (second-order terms are exactly zero for a ReLU network), then the two
// 8x8 RK einsums and the 26-plane output concat.
// ---------------------------------------------------------------------------
__global__ __launch_bounds__(256) void finalize(const float* __restrict__ ws,
                                                const float* __restrict__ rkA,
                                                const float* __restrict__ rkb,
                                                float* __restrict__ outp) {
    const int p = blockIdx.x * 256 + threadIdx.x;   // 16384 threads
    const float* o5 = ws + OFF_OUT5;
    const float* dxy = ws + OFF_DXY;

    const float kap = o5[0 * P + p], v1 = o5[1 * P + p];
    const float v2  = o5[2 * P + p], f  = o5[3 * P + p];
    const float kx  = dxy[0 * P + p], ky  = dxy[1 * P + p];
    const float v1x = dxy[2 * P + p], v1y = dxy[3 * P + p];
    const float v2x = dxy[4 * P + p], v2y = dxy[5 * P + p];
    const float cx = kx + v1, cy = ky + v2;

    float pde[8], urk[8];
#pragma unroll
    for (int q = 0; q < 8; ++q) {
        urk[q] = o5[(4 + q) * P + p];
        float ux = dxy[(6 + 2 * q) * P + p];
        float uy = dxy[(7 + 2 * q) * P + p];
        pde[q] = fmaf(cx, ux, fmaf(cy, uy, f));
    }
#pragma unroll
    for (int r = 0; r < 8; ++r) {
        float si = 0.f, sf = 0.f;
#pragma unroll
        for (int j = 0; j < 8; ++j) {
            float a = rkA[r * 8 + j];
            si = fmaf(a, pde[j], si);
            sf = fmaf(a - rkb[j], pde[j], sf);
        }
        outp[r * P + p] = urk[r] + si;
        outp[(8 + r) * P + p] = urk[r] + sf;
    }
    outp[16 * P + p] = kap;
    outp[17 * P + p] = kx;
    outp[18 * P + p] = ky;
    outp[19 * P + p] = v1;
    outp[20 * P + p] = v1x;
    outp[21 * P + p] = v1y;
    outp[22 * P + p] = v2;
    outp[23 * P + p] = v2x;
    outp[24 * P + p] = v2y;
    outp[25 * P + p] = f;
}

extern "C" void kernel_launch(void* const* d_in, const int* in_sizes, int n_in,
                              void* d_out, int out_size, void* d_ws, size_t ws_size,
                              hipStream_t stream) {
    const float* x   = (const float*)d_in[0];
    const float* y   = (const float*)d_in[1];
    const float* u   = (const float*)d_in[2];
    const float* W1  = (const float*)d_in[3];
    const float* b1  = (const float*)d_in[4];
    const float* W2  = (const float*)d_in[5];
    const float* b2  = (const float*)d_in[6];
    const float* W3  = (const float*)d_in[7];
    const float* b3  = (const float*)d_in[8];
    const float* W4  = (const float*)d_in[9];
    const float* b4  = (const float*)d_in[10];
    const float* W5  = (const float*)d_in[11];
    const float* b5  = (const float*)d_in[12];
    const float* rkA = (const float*)d_in[13];
    const float* rkb = (const float*)d_in[14];

    float* ws   = (float*)d_ws;
    float* outp = (float*)d_out;
    float* wp   = ws + OFF_W;
    float* tbl  = ws + OFF_GA;   // table lives in GA; dz3 consumes it before dz2 overwrites GA

    // 1) repack weights (+ bcot border table) + stage 18-channel input
    pack_weights<<<dim3(57), dim3(256), 0, stream>>>(W1, W2, W3, W4, W5, wp, tbl);
    stage_input<<<dim3(18 * 64), dim3(256), 0, stream>>>(x, y, u, ws + OFF_GB);

    // 2) forward net: r6 geometry (16x16 tiles, 256 thr, COB=4, z=6)
    dim3 blk256(256);
    conv5x5<16, 16, 24, 18, 9, 24, 4, true, false, false, false>
        <<<dim3(8, 8, 6), blk256, 0, stream>>>(
        ws + OFF_GB, wp + PW1, b1, nullptr, nullptr, ws + OFF_H1);
    conv5x5<16, 16, 24, 24, 12, 24, 4, true, false, false, false>
        <<<dim3(8, 8, 6), blk256, 0, stream>>>(
        ws + OFF_H1, wp + PW2, b2, nullptr, nullptr, ws + OFF_H2);
    conv5x5<16, 16, 24, 24, 12, 24, 4, true, false, false, false>
        <<<dim3(8, 8, 6), blk256, 0, stream>>>(
        ws + OFF_H2, wp + PW3, b3, nullptr, nullptr, ws + OFF_H3);
    conv5x5<16, 16, 24, 24, 12, 24, 4, true, false, false, false>
        <<<dim3(8, 8, 6), blk256, 0, stream>>>(
        ws + OFF_H3, wp + PW4, b4, nullptr, nullptr, ws + OFF_H4);
    conv5x5<16, 16, 24, 24, 12, 12, 4, false, false, false, false>
        <<<dim3(8, 8, 3), blk256, 0, stream>>>(
        ws + OFF_H4, wp + PW5, b5, nullptr, nullptr, ws + OFF_OUT5);

    // 3) backward: r6 geometry (256 thr, 16x16, CHUNK=12, COB=12, z=22).
    // dz3 = m3 * (W4^T (*) [m4 * conv5T-table]) — bcot_init folded in via TBL.
    conv5x5<16, 16, 24, 24, 12, 24, 12, false, true, true, true>
        <<<dim3(8, 8, 22), blk256, 0, stream>>>(
        ws + OFF_H4, wp + PB4, nullptr, ws + OFF_H3, tbl, ws + OFF_GB);
    // dz2
    conv5x5<16, 16, 24, 24, 12, 24, 12, false, true, true, false>
        <<<dim3(8, 8, 22), blk256, 0, stream>>>(
        ws + OFF_GB, wp + PB3, nullptr, ws + OFF_H2, nullptr, ws + OFF_GA);
    // dz1
    conv5x5<16, 16, 24, 24, 12, 24, 12, false, true, true, false>
        <<<dim3(8, 8, 22), blk256, 0, stream>>>(
        ws + OFF_GA, wp + PB2, nullptr, ws + OFF_H1, nullptr, ws + OFF_GB);
    // dL/d(x,y): conv1^T restricted to input channels {0,1}
    conv5x5<16, 16, 24, 24, 12, 2, 2, false, false, true, false>
        <<<dim3(8, 8, 11), blk256, 0, stream>>>(
        ws + OFF_GB, wp + PB1, nullptr, nullptr, nullptr, ws + OFF_DXY);

    // 4) pointwise PDE + RK combine + output concat (26 planes)
    finalize<<<dim3(64), blk256, 0, stream>>>(ws, rkA, rkb, outp);
}

// Round 12
// 557.546 us; speedup vs baseline: 1.6361x; 1.6361x over previous
//
#include <hip/hip_runtime.h>

// Problem constants
static constexpr int P = 16384;           // 128*128 plane

// Workspace layout (float offsets). Total ~43.5 MB.
static constexpr int OFF_H1   = 0;         // 24 planes (post-relu act layer1)
static constexpr int OFF_H2   = 24 * P;    // 24
static constexpr int OFF_H3   = 48 * P;    // 24
static constexpr int OFF_H4   = 72 * P;    // 24
static constexpr int OFF_OUT5 = 96 * P;    // 12 (kappa,v1,v2,f,u_rk[8])
static constexpr int OFF_GA   = 108 * P;   // backward ping; ALSO holds bcot table (consumed by dz3 before dz2 overwrites)
static constexpr int OFF_GB   = 372 * P;   // backward pong; also 18-ch input stage
static constexpr int OFF_DXY  = 636 * P;   // 22 planes: per cot [dx, dy] interleaved
static constexpr int OFF_W    = 658 * P;   // packed weights

// packed weight sub-offsets (relative to OFF_W), layout [tap][cin][cout]
static constexpr int PW1 = 0;        // 25*18*24 = 10800
static constexpr int PW2 = 10800;    // 25*24*24 = 14400
static constexpr int PW3 = 25200;
static constexpr int PW4 = 39600;
static constexpr int PW5 = 54000;    // 25*24*12 = 7200
static constexpr int PB4 = 61200;    // transposed+flipped for backward
static constexpr int PB3 = 75600;
static constexpr int PB2 = 90000;
static constexpr int PB1 = 104400;   // 25*24*2 = 1200

// ---------------------------------------------------------------------------
// Repack weights + build the conv5^T one-hot/all-ones cotangent table.
// ---------------------------------------------------------------------------
__global__ void pack_weights(const float* __restrict__ W1, const float* __restrict__ W2,
                             const float* __restrict__ W3, const float* __restrict__ W4,
                             const float* __restrict__ W5, float* __restrict__ wp,
                             float* __restrict__ tbl) {
    int i = blockIdx.x * 256 + threadIdx.x;
    if (i < 10800) {                       // W1p [25][18][24]
        int co = i % 24, ci = (i / 24) % 18, t = i / 432;
        wp[PW1 + i] = W1[(co * 18 + ci) * 25 + t];
    }
    if (i < 14400) {                       // W2p/W3p/W4p + B4/B3/B2
        int co = i % 24, ci = (i / 24) % 24, t = i / 576;
        wp[PW2 + i] = W2[(co * 24 + ci) * 25 + t];
        wp[PW3 + i] = W3[(co * 24 + ci) * 25 + t];
        wp[PW4 + i] = W4[(co * 24 + ci) * 25 + t];
        int cin = i % 24, cout = (i / 24) % 24, tb = i / 576;
        wp[PB4 + i] = W4[(cout * 24 + cin) * 25 + (24 - tb)];
        wp[PB3 + i] = W3[(cout * 24 + cin) * 25 + (24 - tb)];
        wp[PB2 + i] = W2[(cout * 24 + cin) * 25 + (24 - tb)];
    }
    if (i < 7200) {                        // W5p [25][24][12]
        int co = i % 12, ci = (i / 12) % 24, t = i / 288;
        wp[PW5 + i] = W5[(co * 24 + ci) * 25 + t];
    }
    if (i < 1200) {                        // B1 [25][24][2] (only input ch 0,1 needed)
        int ci = i % 2, co = (i / 2) % 24, t = i / 48;
        wp[PB1 + i] = W1[(co * 18 + ci) * 25 + (24 - t)];
    }
    if (i < 6600) {                        // bcot table [11][24][5][5]
        int cx = i % 5, cy = (i / 5) % 5, ci = (i / 25) % 24, cot = i / 600;
        int oc = (cot < 3) ? cot : cot + 1;
        int a0 = (cy <= 2) ? 0 : cy - 2, a1 = (cy >= 2) ? 4 : cy + 2;
        int b0 = (cx <= 2) ? 0 : cx - 2, b1 = (cx >= 2) ? 4 : cx + 2;
        const float* __restrict__ w = W5 + (oc * 24 + ci) * 25;
        float s = 0.f;
        for (int a = a0; a <= a1; ++a)
            for (int b = b0; b <= b1; ++b) s += w[a * 5 + b];
        tbl[i] = s;
    }
}

// Stage x,y,u as a contiguous 18-plane tensor
__global__ void stage_input(const float* __restrict__ x, const float* __restrict__ y,
                            const float* __restrict__ u, float* __restrict__ in18) {
    int i = blockIdx.x * 256 + threadIdx.x;   // 18*P threads
    int pl = i / P, p = i - pl * P;
    float v = (pl == 0) ? x[p] : (pl == 1) ? y[p] : u[(pl - 2) * P + p];
    in18[i] = v;
}

// ---------------------------------------------------------------------------
// Generic 5x5 SAME conv over 128x128 planes.
//  - Geometry: 256 thr, 16x16 tile, CHUNK=12 (r6/r10 Pareto point).
//  - Staging style is now a template knob, set per kernel by MEASUREMENT:
//      PRECOMP=true  (r10): slots precomputed once, batched loads/writes.
//                    Measured best for forward + dxy (-80 us vs r6 style).
//      PRECOMP=false (r6): interleaved div/mod loop. Measured best for the
//                    backward 24ch convs (90 us vs 105 precomp): the address
//                    VALU between dependent load->ds_write pairs fills the
//                    latency holes that batching exposes.
//    (r11's T14 reg-dbuf was defeated by compiler load-sinking — VGPR=40
//     proved rv[] never stayed live; reverted.)
//  - halo LDS stride SW=24 -> 2-way bank aliasing on FMA reads (free).
//  - weights packed [tap][cin][cout]; inner co loop reads contiguous
//    block-uniform addresses -> s_load, SGPR operand in v_fmac.
//  - BATCH: blockIdx.z folds (cotangent, channel-split).
//  - MASK: multiply output by (mask_plane > 0) -> relu backward.
//  - TBL: stage (h4>0 ? border-class table : 0) (bcot_init folded into dz3;
//    'inbase' is h4, unbatched).
// ---------------------------------------------------------------------------
template <int NTY, int TW, int SW, int CIN, int CHUNK, int COUT_TOT, int COB,
          bool RELU, bool MASK, bool BATCH, bool TBL, bool PRECOMP>
__global__ __launch_bounds__(NTY * TW, 7) void conv5x5(
    const float* __restrict__ inbase, const float* __restrict__ wp,
    const float* __restrict__ bias, const float* __restrict__ maskbase,
    const float* __restrict__ tbl, float* __restrict__ outbase) {
    constexpr int NSPL = COUT_TOT / COB;
    constexpr int TR = NTY;                // tile rows
    constexpr int HR = TR + 4;             // halo rows
    constexpr int HC = TW + 4;             // halo cols (logical)
    constexpr int NT = NTY * TW;           // threads
    constexpr int HTOT = HR * HC;          // halo elements per channel
    constexpr int NSLOT = (HTOT + NT - 1) / NT;
    const int z = blockIdx.z;
    const int half = z % NSPL;
    const int cot = z / NSPL;
    const float* in = inbase + ((BATCH && !TBL) ? cot * CIN * P : 0);
    float* out = outbase + (BATCH ? cot * COUT_TOT * P : 0);
    const int cobase = half * COB;

    __shared__ float smem[CHUNK][HR][SW];
    const int tid = threadIdx.x;
    const int bx = blockIdx.x, by = blockIdx.y;
    const int ty = tid / TW, tx = tid % TW;

    // ---- precomputed staging slots (PRECOMP only) ----
    bool s_store[NSLOT];
    bool s_valid[NSLOT];
    int  s_goff[NSLOT];
    int  s_lds[NSLOT];
    int  s_tcls[NSLOT];
    if (PRECOMP) {
#pragma unroll
        for (int s = 0; s < NSLOT; ++s) {
            int i = tid + s * NT;
            int r = i / HC, c = i % HC;
            int gy = by * TR + r - 2, gx = bx * TW + c - 2;
            s_store[s] = (i < HTOT);
            s_valid[s] = (i < HTOT) && ((unsigned)gy < 128u) && ((unsigned)gx < 128u);
            s_goff[s]  = s_valid[s] ? (gy * 128 + gx) : 0;
            s_lds[s]   = r * SW + c;
            if (TBL) {
                int cy = (gy < 2) ? gy : (gy > 125) ? gy - 123 : 2;
                int cx = (gx < 2) ? gx : (gx > 125) ? gx - 123 : 2;
                s_tcls[s] = cy * 5 + cx;
            }
        }
    }

    float acc[COB];
#pragma unroll
    for (int co = 0; co < COB; ++co) acc[co] = bias ? bias[cobase + co] : 0.f;

    for (int c0 = 0; c0 < CIN; c0 += CHUNK) {
        if (c0) __syncthreads();           // previous chunk's compute must finish
        if (PRECOMP) {
#pragma unroll
            for (int s = 0; s < NSLOT; ++s) {
                if (s_store[s]) {
                    float* lbase = &smem[0][0][0] + s_lds[s];
                    const float* gbase = in + c0 * P + s_goff[s];
#pragma unroll
                    for (int ci = 0; ci < CHUNK; ++ci) {
                        float v = 0.f;
                        if (s_valid[s]) {
                            if (TBL) {
                                float m = gbase[ci * P];
                                if (m > 0.f)
                                    v = tbl[(cot * CIN + c0 + ci) * 25 + s_tcls[s]];
                            } else {
                                v = gbase[ci * P];
                            }
                        }
                        lbase[ci * HR * SW] = v;
                    }
                }
            }
        } else {
            for (int i = tid; i < CHUNK * HTOT; i += NT) {
                int ci = i / HTOT, rem = i - ci * HTOT;
                int r = rem / HC, c = rem - r * HC;
                int gy = by * TR + r - 2, gx = bx * TW + c - 2;
                float v = 0.f;
                if ((unsigned)gy < 128u && (unsigned)gx < 128u) {
                    if (TBL) {
                        float m = in[(c0 + ci) * P + gy * 128 + gx];
                        if (m > 0.f) {
                            int cy = (gy < 2) ? gy : (gy > 125) ? gy - 123 : 2;
                            int cx = (gx < 2) ? gx : (gx > 125) ? gx - 123 : 2;
                            v = tbl[((cot * CIN + c0 + ci) * 5 + cy) * 5 + cx];
                        }
                    } else {
                        v = in[(c0 + ci) * P + gy * 128 + gx];
                    }
                }
                smem[ci][r][c] = v;
            }
        }
        __syncthreads();

        for (int a = 0; a < 5; ++a) {
            for (int b = 0; b < 5; ++b) {
                const float* __restrict__ wrow =
                    wp + ((a * 5 + b) * CIN + c0) * COUT_TOT + cobase;
                for (int ci = 0; ci < CHUNK; ++ci) {
                    float v = smem[ci][ty + a][tx + b];
#pragma unroll
                    for (int co = 0; co < COB; ++co)
                        acc[co] = fmaf(v, wrow[ci * COUT_TOT + co], acc[co]);
                }
            }
        }
    }

    const int gy = by * TR + ty, gx = bx * TW + tx, gp = gy * 128 + gx;
#pragma unroll
    for (int co = 0; co < COB; ++co) {
        float v = acc[co];
        if (RELU) v = v > 0.f ? v : 0.f;
        if (MASK) v = (maskbase[(cobase + co) * P + gp] > 0.f) ? v : 0.f;
        out[(cobase + co) * P + gp] = v;
    }
}

// ---------------------------------------------------------------------------
// Finalize: pde[q] = (kappa_x+v1)*u_rk_x[q] + (kappa_y+v2)*u_rk_y[q] + f
// (second-order terms are exactly zero for a ReLU network), then the two
// 8x8 RK einsums and the 26-plane output concat.
// ---------------------------------------------------------------------------
__global__ __launch_bounds__(256) void finalize(const float* __restrict__ ws,
                                                const float* __restrict__ rkA,
                                                const float* __restrict__ rkb,
                                                float* __restrict__ outp) {
    const int p = blockIdx.x * 256 + threadIdx.x;   // 16384 threads
    const float* o5 = ws + OFF_OUT5;
    const float* dxy = ws + OFF_DXY;

    const float kap = o5[0 * P + p], v1 = o5[1 * P + p];
    const float v2  = o5[2 * P + p], f  = o5[3 * P + p];
    const float kx  = dxy[0 * P + p], ky  = dxy[1 * P + p];
    const float v1x = dxy[2 * P + p], v1y = dxy[3 * P + p];
    const float v2x = dxy[4 * P + p], v2y = dxy[5 * P + p];
    const float cx = kx + v1, cy = ky + v2;

    float pde[8], urk[8];
#pragma unroll
    for (int q = 0; q < 8; ++q) {
        urk[q] = o5[(4 + q) * P + p];
        float ux = dxy[(6 + 2 * q) * P + p];
        float uy = dxy[(7 + 2 * q) * P + p];
        pde[q] = fmaf(cx, ux, fmaf(cy, uy, f));
    }
#pragma unroll
    for (int r = 0; r < 8; ++r) {
        float si = 0.f, sf = 0.f;
#pragma unroll
        for (int j = 0; j < 8; ++j) {
            float a = rkA[r * 8 + j];
            si = fmaf(a, pde[j], si);
            sf = fmaf(a - rkb[j], pde[j], sf);
        }
        outp[r * P + p] = urk[r] + si;
        outp[(8 + r) * P + p] = urk[r] + sf;
    }
    outp[16 * P + p] = kap;
    outp[17 * P + p] = kx;
    outp[18 * P + p] = ky;
    outp[19 * P + p] = v1;
    outp[20 * P + p] = v1x;
    outp[21 * P + p] = v1y;
    outp[22 * P + p] = v2;
    outp[23 * P + p] = v2x;
    outp[24 * P + p] = v2y;
    outp[25 * P + p] = f;
}

extern "C" void kernel_launch(void* const* d_in, const int* in_sizes, int n_in,
                              void* d_out, int out_size, void* d_ws, size_t ws_size,
                              hipStream_t stream) {
    const float* x   = (const float*)d_in[0];
    const float* y   = (const float*)d_in[1];
    const float* u   = (const float*)d_in[2];
    const float* W1  = (const float*)d_in[3];
    const float* b1  = (const float*)d_in[4];
    const float* W2  = (const float*)d_in[5];
    const float* b2  = (const float*)d_in[6];
    const float* W3  = (const float*)d_in[7];
    const float* b3  = (const float*)d_in[8];
    const float* W4  = (const float*)d_in[9];
    const float* b4  = (const float*)d_in[10];
    const float* W5  = (const float*)d_in[11];
    const float* b5  = (const float*)d_in[12];
    const float* rkA = (const float*)d_in[13];
    const float* rkb = (const float*)d_in[14];

    float* ws   = (float*)d_ws;
    float* outp = (float*)d_out;
    float* wp   = ws + OFF_W;
    float* tbl  = ws + OFF_GA;   // table lives in GA; dz3 consumes it before dz2 overwrites GA

    // 1) repack weights (+ bcot border table) + stage 18-channel input
    pack_weights<<<dim3(57), dim3(256), 0, stream>>>(W1, W2, W3, W4, W5, wp, tbl);
    stage_input<<<dim3(18 * 64), dim3(256), 0, stream>>>(x, y, u, ws + OFF_GB);

    // 2) forward net: r10 config (16x16 tiles, 256 thr, COB=4, z=6, PRECOMP)
    dim3 blk256(256);
    conv5x5<16, 16, 24, 18, 9, 24, 4, true, false, false, false, true>
        <<<dim3(8, 8, 6), blk256, 0, stream>>>(
        ws + OFF_GB, wp + PW1, b1, nullptr, nullptr, ws + OFF_H1);
    conv5x5<16, 16, 24, 24, 12, 24, 4, true, false, false, false, true>
        <<<dim3(8, 8, 6), blk256, 0, stream>>>(
        ws + OFF_H1, wp + PW2, b2, nullptr, nullptr, ws + OFF_H2);
    conv5x5<16, 16, 24, 24, 12, 24, 4, true, false, false, false, true>
        <<<dim3(8, 8, 6), blk256, 0, stream>>>(
        ws + OFF_H2, wp + PW3, b3, nullptr, nullptr, ws + OFF_H3);
    conv5x5<16, 16, 24, 24, 12, 24, 4, true, false, false, false, true>
        <<<dim3(8, 8, 6), blk256, 0, stream>>>(
        ws + OFF_H3, wp + PW4, b4, nullptr, nullptr, ws + OFF_H4);
    conv5x5<16, 16, 24, 24, 12, 12, 4, false, false, false, false, true>
        <<<dim3(8, 8, 3), blk256, 0, stream>>>(
        ws + OFF_H4, wp + PW5, b5, nullptr, nullptr, ws + OFF_OUT5);

    // 3) backward: r6 config (256 thr, 16x16, CHUNK=12, COB=12, z=22,
    //    div/mod staging = measured 90 us vs 105 precomp).
    // dz3 = m3 * (W4^T (*) [m4 * conv5T-table]) — bcot_init folded in via TBL.
    conv5x5<16, 16, 24, 24, 12, 24, 12, false, true, true, true, false>
        <<<dim3(8, 8, 22), blk256, 0, stream>>>(
        ws + OFF_H4, wp + PB4, nullptr, ws + OFF_H3, tbl, ws + OFF_GB);
    // dz2
    conv5x5<16, 16, 24, 24, 12, 24, 12, false, true, true, false, false>
        <<<dim3(8, 8, 22), blk256, 0, stream>>>(
        ws + OFF_GB, wp + PB3, nullptr, ws + OFF_H2, nullptr, ws + OFF_GA);
    // dz1
    conv5x5<16, 16, 24, 24, 12, 24, 12, false, true, true, false, false>
        <<<dim3(8, 8, 22), blk256, 0, stream>>>(
        ws + OFF_GA, wp + PB2, nullptr, ws + OFF_H1, nullptr, ws + OFF_GB);
    // dL/d(x,y): conv1^T restricted to input channels {0,1} (r10 PRECOMP)
    conv5x5<16, 16, 24, 24, 12, 2, 2, false, false, true, false, true>
        <<<dim3(8, 8, 11), blk256, 0, stream>>>(
        ws + OFF_GB, wp + PB1, nullptr, nullptr, nullptr, ws + OFF_DXY);

    // 4) pointwise PDE + RK combine + output concat (26 planes)
    finalize<<<dim3(64), blk256, 0, stream>>>(ws, rkA, rkb, outp);
}